// Round 2
// baseline (134.160 us; speedup 1.0000x reference)
//
#include <hip/hip_runtime.h>
#include <hip/hip_bf16.h>

#define DIM   512
#define NHEAD 8
#define DM    64
#define DL    128
#define BBAG  8
#define NINST 4096
#define MTOT  (BBAG*NINST)     // 32768 instances
#define NCOL  (NHEAD*DM + DL)  // 640 fused output columns (8*64 mh + 128 gate)
#define NCHUNK 8               // pool n-chunks per (h,b)

typedef short   bf16x8 __attribute__((ext_vector_type(8)));
typedef __bf16  bf16v8 __attribute__((ext_vector_type(8)));
typedef float   f32x4  __attribute__((ext_vector_type(4)));
typedef short   s16x4  __attribute__((ext_vector_type(4)));

__device__ __forceinline__ short f2b(float f) {
  __hip_bfloat16 h = __float2bfloat16(f);
  return __builtin_bit_cast(short, h);
}
__device__ __forceinline__ float b2f(short s) {
  __hip_bfloat16 h = __builtin_bit_cast(__hip_bfloat16, s);
  return __bfloat162float(h);
}
__device__ __forceinline__ f32x4 mfma_bf16(bf16x8 a, bf16x8 b, f32x4 c) {
  return __builtin_amdgcn_mfma_f32_16x16x32_bf16(
      __builtin_bit_cast(bf16v8, a), __builtin_bit_cast(bf16v8, b), c, 0, 0, 0);
}

// ---------------------------------------------------------------------------
// Kernel 1: cast weights to bf16, k-contiguous layouts for MFMA B-fragments.
// Wt[col][k], col<512 -> WX[h=col>>6][k][m=col&63]; col>=512 -> gate_w[k][col-512]
// Vt[l][m] = V[m][l]
// ---------------------------------------------------------------------------
__global__ void prep_weights(const float* __restrict__ WX, const float* __restrict__ V,
                             const float* __restrict__ gate_w,
                             short* __restrict__ Wt, short* __restrict__ Vt) {
  int g = blockIdx.x * blockDim.x + threadIdx.x;
  if (g < NCOL * DIM) {
    int col = g >> 9, k = g & 511;
    float v;
    if (col < NHEAD * DM) v = WX[((size_t)(col >> 6) * DIM + k) * DM + (col & 63)];
    else                  v = gate_w[(size_t)k * DL + (col - NHEAD * DM)];
    Wt[(size_t)col * DIM + k] = f2b(v);
  } else {
    int i = g - NCOL * DIM;
    if (i < DL * DM) {
      int l = i >> 6, m = i & 63;
      Vt[(size_t)l * DM + m] = f2b(V[(size_t)m * DL + l]);
    }
  }
}

// ---------------------------------------------------------------------------
// Kernel 2: fused projection GEMM  C[32768 x 640] = x[32768 x 512] * Wcat
// 64-row tile/block, 512 threads (8 waves), waves split 640 cols (80 each).
// A (x rows) staged f32->bf16 in LDS (padded stride 520 shorts => no conflicts).
// cols < 512 -> mh[h][row][m] bf16 ; cols >= 512 -> gate[row][l] = sigmoid.
// ---------------------------------------------------------------------------
#define BM 64
#define LDST 520  // shorts per LDS row (512 + 8 pad); 1040 B, 16B-aligned

__global__ __launch_bounds__(512, 2) void proj_kernel(
    const float* __restrict__ x, const short* __restrict__ Wt,
    short* __restrict__ mh, short* __restrict__ gate) {
  __shared__ alignas(16) short lds_a[BM * LDST];
  const int tid = threadIdx.x;
  const int bm0 = blockIdx.x * BM;

  // stage 64 rows x 512 of x: f32 global -> bf16 LDS
  const float4* xsrc = reinterpret_cast<const float4*>(x + (size_t)bm0 * DIM);
  #pragma unroll
  for (int i = 0; i < 16; ++i) {
    int fidx = i * 512 + tid;        // float4 index in [0, 8192)
    float4 v = xsrc[fidx];
    int e = fidx * 4;
    int row = e >> 9, kk = e & 511;
    s16x4 s; s.x = f2b(v.x); s.y = f2b(v.y); s.z = f2b(v.z); s.w = f2b(v.w);
    *reinterpret_cast<s16x4*>(reinterpret_cast<char*>(lds_a) + row * (LDST * 2) + kk * 2) = s;
  }
  __syncthreads();

  const int lane = tid & 63;
  const int w = tid >> 6;            // wave 0..7 -> cols [80w, 80w+80)
  const int r = lane & 15;
  const int q = lane >> 4;           // 0..3

  f32x4 acc[4][5];
  #pragma unroll
  for (int rt = 0; rt < 4; ++rt)
    #pragma unroll
    for (int ct = 0; ct < 5; ++ct) acc[rt][ct] = f32x4{0.f, 0.f, 0.f, 0.f};

  const int col_base = w * 80;
  for (int ks = 0; ks < 16; ++ks) {       // K = 512 in steps of 32
    bf16x8 af[4];
    #pragma unroll
    for (int rt = 0; rt < 4; ++rt) {
      const char* p = reinterpret_cast<const char*>(lds_a)
                    + (16 * rt + r) * (LDST * 2) + ks * 64 + q * 16;
      af[rt] = *reinterpret_cast<const bf16x8*>(p);
    }
    #pragma unroll
    for (int ct = 0; ct < 5; ++ct) {
      const short* bp = Wt + (size_t)(col_base + 16 * ct + r) * DIM + ks * 32 + q * 8;
      bf16x8 bf = *reinterpret_cast<const bf16x8*>(bp);
      #pragma unroll
      for (int rt = 0; rt < 4; ++rt)
        acc[rt][ct] = mfma_bf16(af[rt], bf, acc[rt][ct]);
    }
  }

  // epilogue: D-frag lane mapping row = 4q+j (+16rt), col = r (+16ct)
  #pragma unroll
  for (int rt = 0; rt < 4; ++rt) {
    #pragma unroll
    for (int ct = 0; ct < 5; ++ct) {
      int col = col_base + 16 * ct + r;
      #pragma unroll
      for (int j = 0; j < 4; ++j) {
        int grow = bm0 + 16 * rt + 4 * q + j;
        float v = acc[rt][ct][j];
        if (col < NHEAD * DM) {
          mh[((size_t)(col >> 6) * MTOT + grow) * DM + (col & 63)] = f2b(v);
        } else {
          gate[(size_t)grow * DL + (col - NHEAD * DM)] = f2b(1.0f / (1.0f + expf(-v)));
        }
      }
    }
  }
}

// ---------------------------------------------------------------------------
// Kernel 3: scores[h][row] = sum_l tanh( (mh_h . V)[row][l] ) * gate[row][l] * W[h][l]
// 64-row tile/block, 256 threads (4 waves), each wave does 2 heads.
// ---------------------------------------------------------------------------
__global__ __launch_bounds__(256) void score_kernel(
    const short* __restrict__ mh, const short* __restrict__ gate,
    const short* __restrict__ Vt, const float* __restrict__ W,
    float* __restrict__ scores) {
  const int tid = threadIdx.x;
  const int lane = tid & 63;
  const int wv = tid >> 6;         // 0..3
  const int r = lane & 15, q = lane >> 4;
  const int row0 = blockIdx.x * 64;

  #pragma unroll
  for (int hh = 0; hh < 2; ++hh) {
    const int h = wv * 2 + hh;
    float wc[8];
    #pragma unroll
    for (int ct = 0; ct < 8; ++ct) wc[ct] = W[(size_t)h * DL + 16 * ct + r];

    #pragma unroll
    for (int rt = 0; rt < 4; ++rt) {
      const short* ap = mh + ((size_t)h * MTOT + row0 + 16 * rt + r) * DM + q * 8;
      bf16x8 a0 = *reinterpret_cast<const bf16x8*>(ap);
      bf16x8 a1 = *reinterpret_cast<const bf16x8*>(ap + 32);
      float sc[4] = {0.f, 0.f, 0.f, 0.f};
      #pragma unroll
      for (int ct = 0; ct < 8; ++ct) {
        const short* bp = Vt + (size_t)(16 * ct + r) * DM + q * 8;
        bf16x8 b0 = *reinterpret_cast<const bf16x8*>(bp);
        bf16x8 b1 = *reinterpret_cast<const bf16x8*>(bp + 32);
        f32x4 t = f32x4{0.f, 0.f, 0.f, 0.f};
        t = mfma_bf16(a0, b0, t);
        t = mfma_bf16(a1, b1, t);
        #pragma unroll
        for (int j = 0; j < 4; ++j) {
          int row = row0 + 16 * rt + 4 * q + j;
          int coll = 16 * ct + r;
          float g = b2f(gate[(size_t)row * DL + coll]);
          float d = tanhf(t[j]) * g;
          sc[j] += d * wc[ct];
        }
      }
      #pragma unroll
      for (int j = 0; j < 4; ++j) {
        sc[j] += __shfl_xor(sc[j], 1);
        sc[j] += __shfl_xor(sc[j], 2);
        sc[j] += __shfl_xor(sc[j], 4);
        sc[j] += __shfl_xor(sc[j], 8);
      }
      if (r < 4) {
        float v = (r == 0) ? sc[0] : (r == 1) ? sc[1] : (r == 2) ? sc[2] : sc[3];
        scores[(size_t)h * MTOT + row0 + 16 * rt + 4 * q + r] = v;
      }
    }
  }
}

// ---------------------------------------------------------------------------
// Kernel 4: masked softmax over N per (h,b). soft=0 for n >= true_num[b].
// Also writes head-0 softmax to the output (second tuple element).
// ---------------------------------------------------------------------------
__global__ __launch_bounds__(256) void softmax_kernel(
    const float* __restrict__ scores, const int* __restrict__ true_num,
    float* __restrict__ soft, float* __restrict__ out_soft) {
  const int h = blockIdx.x >> 3, b = blockIdx.x & 7;
  const int tid = threadIdx.x;
  const int tn = true_num[b];
  const float* s = scores + ((size_t)h * BBAG + b) * NINST;
  __shared__ float red[8];

  float vals[16];
  float mx = -3.0e38f;
  #pragma unroll
  for (int i = 0; i < 16; ++i) {
    int n = tid + i * 256;
    float v = s[n];
    vals[i] = (n < tn) ? v : -3.0e38f;
    mx = fmaxf(mx, vals[i]);
  }
  #pragma unroll
  for (int m = 1; m < 64; m <<= 1) mx = fmaxf(mx, __shfl_xor(mx, m));
  if ((tid & 63) == 0) red[tid >> 6] = mx;
  __syncthreads();
  mx = fmaxf(fmaxf(red[0], red[1]), fmaxf(red[2], red[3]));

  float sum = 0.f;
  #pragma unroll
  for (int i = 0; i < 16; ++i) {
    int n = tid + i * 256;
    float e = (n < tn) ? expf(vals[i] - mx) : 0.0f;
    vals[i] = e;
    sum += e;
  }
  #pragma unroll
  for (int m = 1; m < 64; m <<= 1) sum += __shfl_xor(sum, m);
  if ((tid & 63) == 0) red[4 + (tid >> 6)] = sum;
  __syncthreads();
  sum = red[4] + red[5] + red[6] + red[7];
  float inv = 1.0f / sum;

  float* so = soft + ((size_t)h * BBAG + b) * NINST;
  #pragma unroll
  for (int i = 0; i < 16; ++i) {
    int n = tid + i * 256;
    float v = vals[i] * inv;
    so[n] = v;
    if (h == 0) out_soft[(size_t)b * NINST + n] = v;
  }
}

// ---------------------------------------------------------------------------
// Kernel 5a: partial pooling. grid = (h,b,chunk): 8*8*8 = 512 blocks.
// part[(h*8+b)*NCHUNK+chunk][m] = sum_{n in chunk} soft[h][b][n]*mh[h][b*N+n][m]
// ---------------------------------------------------------------------------
__global__ __launch_bounds__(256) void pool_partial(
    const short* __restrict__ mh, const float* __restrict__ soft,
    float* __restrict__ part) {
  const int c = blockIdx.x & (NCHUNK - 1);
  const int hb = blockIdx.x / NCHUNK;        // h*8 + b
  const int h = hb >> 3, b = hb & 7;
  const int tid = threadIdx.x;
  const int m = tid & 63, g = tid >> 6;
  const int n0 = c * (NINST / NCHUNK);
  const float* so = soft + ((size_t)h * BBAG + b) * NINST;
  const short* mp = mh + ((size_t)h * MTOT + (size_t)b * NINST) * DM;
  float acc = 0.f;
  #pragma unroll 4
  for (int n = n0 + g; n < n0 + NINST / NCHUNK; n += 4) {
    acc += so[n] * b2f(mp[(size_t)n * DM + m]);
  }
  __shared__ float red[256];
  red[tid] = acc;
  __syncthreads();
  if (tid < 64) {
    part[(size_t)(hb * NCHUNK + c) * DM + tid] =
        red[tid] + red[tid + 64] + red[tid + 128] + red[tid + 192];
  }
}

// ---------------------------------------------------------------------------
// Kernel 5b: reduce partials -> feat[b][h*64+m]
// ---------------------------------------------------------------------------
__global__ __launch_bounds__(256) void pool_reduce(
    const float* __restrict__ part, float* __restrict__ out_feat) {
  int g = blockIdx.x * blockDim.x + threadIdx.x;   // 4096 outputs
  int hb = g >> 6, m = g & 63;
  int h = hb >> 3, b = hb & 7;
  float s = 0.f;
  #pragma unroll
  for (int c = 0; c < NCHUNK; ++c)
    s += part[(size_t)(hb * NCHUNK + c) * DM + m];
  out_feat[(size_t)b * (NHEAD * DM) + h * DM + m] = s;
}

// ---------------------------------------------------------------------------
extern "C" void kernel_launch(void* const* d_in, const int* in_sizes, int n_in,
                              void* d_out, int out_size, void* d_ws, size_t ws_size,
                              hipStream_t stream) {
  (void)in_sizes; (void)n_in; (void)out_size; (void)ws_size;
  const float* x      = (const float*)d_in[0];
  const float* WX     = (const float*)d_in[1];
  const float* V      = (const float*)d_in[2];
  const float* W      = (const float*)d_in[3];
  const float* gate_w = (const float*)d_in[4];
  const int* true_num = (const int*)d_in[5];
  float* out = (float*)d_out;

  char* ws = (char*)d_ws;
  short* Wt     = (short*)ws;  ws += (size_t)NCOL * DIM * 2;            //    655,360 B
  short* Vt     = (short*)ws;  ws += (size_t)DL * DM * 2;               //     16,384 B
  short* mh     = (short*)ws;  ws += (size_t)NHEAD * MTOT * DM * 2;     // 33,554,432 B
  short* gate   = (short*)ws;  ws += (size_t)MTOT * DL * 2;             //  8,388,608 B
  float* scores = (float*)ws;  ws += (size_t)NHEAD * MTOT * 4;          //  1,048,576 B
  float* soft   = (float*)ws;  ws += (size_t)NHEAD * MTOT * 4;          //  1,048,576 B
  float* part   = (float*)ws;  ws += (size_t)NHEAD * BBAG * NCHUNK * DM * 4; // 131,072 B
  // total ~44.8 MB of d_ws

  prep_weights<<<dim3((NCOL * DIM + DL * DM + 255) / 256), dim3(256), 0, stream>>>(
      WX, V, gate_w, Wt, Vt);
  proj_kernel<<<dim3(MTOT / BM), dim3(512), 0, stream>>>(x, Wt, mh, gate);
  score_kernel<<<dim3(MTOT / 64), dim3(256), 0, stream>>>(mh, gate, Vt, W, scores);
  softmax_kernel<<<dim3(NHEAD * BBAG), dim3(256), 0, stream>>>(
      scores, true_num, soft, out + BBAG * NHEAD * DM);
  pool_partial<<<dim3(NHEAD * BBAG * NCHUNK), dim3(256), 0, stream>>>(mh, soft, part);
  pool_reduce<<<dim3(NHEAD * BBAG * DM / 256), dim3(256), 0, stream>>>(part, out);
}

// Round 5
// 119.995 us; speedup vs baseline: 1.1180x; 1.1180x over previous
//
#include <hip/hip_runtime.h>
#include <hip/hip_bf16.h>

#define DIM   512
#define NHEAD 8
#define DM    64
#define DL    128
#define BBAG  8
#define NINST 4096
#define MTOT  (BBAG*NINST)     // 32768 instances
#define NCOL  (NHEAD*DM + DL)  // 640 fused output columns (8*64 mh + 128 gate)
#define NCHUNK 8               // pool n-chunks per (h,b)

typedef short   bf16x8 __attribute__((ext_vector_type(8)));
typedef __bf16  bf16v8 __attribute__((ext_vector_type(8)));
typedef float   f32x4  __attribute__((ext_vector_type(4)));
typedef short   s16x4  __attribute__((ext_vector_type(4)));

__device__ __forceinline__ short f2b(float f) {
  __hip_bfloat16 h = __float2bfloat16(f);
  return __builtin_bit_cast(short, h);
}
__device__ __forceinline__ float b2f(short s) {
  __hip_bfloat16 h = __builtin_bit_cast(__hip_bfloat16, s);
  return __bfloat162float(h);
}
__device__ __forceinline__ f32x4 mfma_bf16(bf16x8 a, bf16x8 b, f32x4 c) {
  return __builtin_amdgcn_mfma_f32_16x16x32_bf16(
      __builtin_bit_cast(bf16v8, a), __builtin_bit_cast(bf16v8, b), c, 0, 0, 0);
}

// ---------------------------------------------------------------------------
// Kernel 1: build bf16 weights.
// Wt2: slab-major, swizzled: for K-step ks (32 k), col, k-quarter q (8 bf16):
//   stored at shorts[ks*20480 + col*32 + q2*8], q2 = (q + ((col&15)>>1)) & 3.
//   Slab ks is 40 KB CONTIGUOUS -> global_load_lds coalesced; swizzle makes
//   ds_read_b128 fragment reads bank-conflict-free (2 lanes/bank-quad/phase).
// Vt[l][m] = V[m][l]  (k-contiguous for score kernel B-frags)
// ---------------------------------------------------------------------------
__global__ void prep_weights(const float* __restrict__ WX, const float* __restrict__ V,
                             const float* __restrict__ gate_w,
                             short* __restrict__ Wt2, short* __restrict__ Vt) {
  int g = blockIdx.x * blockDim.x + threadIdx.x;
  if (g < 16 * 640 * 4) {               // 40960 16-byte pieces of Wt2
    int ks = g / 2560;
    int rem = g - ks * 2560;
    int col = rem >> 2, q = rem & 3;
    int q2 = (q + ((col & 15) >> 1)) & 3;
    short* dst = Wt2 + ks * 20480 + col * 32 + q2 * 8;
    #pragma unroll
    for (int j = 0; j < 8; ++j) {
      int k = ks * 32 + q * 8 + j;
      float v;
      if (col < NHEAD * DM) v = WX[((size_t)(col >> 6) * DIM + k) * DM + (col & 63)];
      else                  v = gate_w[(size_t)k * DL + (col - NHEAD * DM)];
      dst[j] = f2b(v);
    }
  } else {
    int i = g - 16 * 640 * 4;
    if (i < DL * DM) {
      int l = i >> 6, m = i & 63;
      Vt[(size_t)l * DM + m] = f2b(V[(size_t)m * DL + l]);
    }
  }
}

// ---------------------------------------------------------------------------
// Kernel 2: fused projection GEMM  C[32768 x 640] = x[32768 x 512] * Wcat
// 64-row tile/block, 512 threads (8 waves), waves split 640 cols (80 each).
// Per K-step (BK=32): B slab (40 KB) -> LDS via global_load_lds width=16
// (pre-swizzled source, linear dest); A (64x32 f32) reg-staged f32->bf16.
// 2-barrier single-buffer loop (m97 structure). LDS total 44 KB.
// ---------------------------------------------------------------------------
__global__ __launch_bounds__(512) void proj_kernel(
    const float* __restrict__ x, const short* __restrict__ Wt2,
    short* __restrict__ mh, short* __restrict__ gate) {
  __shared__ alignas(1024) short lds_b[20480];  // 40 KB: [640 cols][32 k] swizzled
  __shared__ alignas(16)   short lds_a[2048];   //  4 KB: [64 rows][32 k] swizzled
  const int tid = threadIdx.x;
  const int bm0 = blockIdx.x * 64;
  const int lane = tid & 63;
  const int w = tid >> 6;            // wave 0..7 -> cols [80w, 80w+80)
  const int r = lane & 15;
  const int q = lane >> 4;           // 0..3
  const int swz = ((q + (r >> 1)) & 3) * 16;  // bank-quad swizzle byte offset

  // A-staging assignment (fixed per thread): row, 16B-f32 piece
  const int arow = tid >> 3, ap = tid & 7;
  const int aslot = ((ap >> 1) + ((arow & 15) >> 1)) & 3;
  char* lda = reinterpret_cast<char*>(lds_a);
  char* ldb = reinterpret_cast<char*>(lds_b);
  const float* asrc = x + ((size_t)(bm0 + arow) << 9) + (ap << 2);
  char* adst = lda + arow * 64 + aslot * 16 + (ap & 1) * 8;

  f32x4 acc[4][5];
  #pragma unroll
  for (int rt = 0; rt < 4; ++rt)
    #pragma unroll
    for (int ct = 0; ct < 5; ++ct) acc[rt][ct] = f32x4{0.f, 0.f, 0.f, 0.f};

  for (int ks = 0; ks < 16; ++ks) {
    // --- stage B: 5 x global_load_lds (1 KB per wave-instr, coalesced) ---
    #pragma unroll
    for (int i = 0; i < 5; ++i) {
      const int unit = w * 5 + i;                      // 0..39 KB-units
      const short* gsrc = Wt2 + ks * 20480 + unit * 512 + lane * 8;
      __builtin_amdgcn_global_load_lds(
          (const __attribute__((address_space(1))) void*)gsrc,
          (__attribute__((address_space(3))) void*)(ldb + unit * 1024),
          16, 0, 0);
    }
    // --- stage A: f32x4 -> 4 bf16 -> ds_write 8B (swizzled) ---
    float4 av = *reinterpret_cast<const float4*>(asrc + ks * 32);
    s16x4 as;
    as.x = f2b(av.x); as.y = f2b(av.y); as.z = f2b(av.z); as.w = f2b(av.w);
    *reinterpret_cast<s16x4*>(adst) = as;
    __syncthreads();

    // --- compute: 4 A-frags, 5 B-frags, 20 MFMA ---
    bf16x8 af[4];
    #pragma unroll
    for (int rt = 0; rt < 4; ++rt)
      af[rt] = *reinterpret_cast<const bf16x8*>(lda + (16 * rt + r) * 64 + swz);
    #pragma unroll
    for (int ct = 0; ct < 5; ++ct) {
      bf16x8 bf = *reinterpret_cast<const bf16x8*>(
          ldb + (80 * w + 16 * ct + r) * 64 + swz);
      #pragma unroll
      for (int rt = 0; rt < 4; ++rt)
        acc[rt][ct] = mfma_bf16(af[rt], bf, acc[rt][ct]);
    }
    __syncthreads();
  }

  // epilogue: D-frag lane mapping row = 4q+j (+16rt), col = r (+16ct)
  #pragma unroll
  for (int rt = 0; rt < 4; ++rt) {
    #pragma unroll
    for (int ct = 0; ct < 5; ++ct) {
      int col = 80 * w + 16 * ct + r;
      #pragma unroll
      for (int j = 0; j < 4; ++j) {
        int grow = bm0 + 16 * rt + 4 * q + j;
        float v = acc[rt][ct][j];
        if (col < NHEAD * DM) {
          mh[((size_t)(col >> 6) * MTOT + grow) * DM + (col & 63)] = f2b(v);
        } else {
          gate[(size_t)grow * DL + (col - NHEAD * DM)] = f2b(1.0f / (1.0f + expf(-v)));
        }
      }
    }
  }
}

// ---------------------------------------------------------------------------
// Kernel 3: scores[h][row] = sum_l tanh( (mh_h . V)[row][l] ) * gate[row][l] * W[h][l]
// 64-row tile/block, 256 threads (4 waves), each wave does 2 heads.
// ---------------------------------------------------------------------------
__global__ __launch_bounds__(256) void score_kernel(
    const short* __restrict__ mh, const short* __restrict__ gate,
    const short* __restrict__ Vt, const float* __restrict__ W,
    float* __restrict__ scores) {
  const int tid = threadIdx.x;
  const int lane = tid & 63;
  const int wv = tid >> 6;         // 0..3
  const int r = lane & 15, q = lane >> 4;
  const int row0 = blockIdx.x * 64;

  #pragma unroll
  for (int hh = 0; hh < 2; ++hh) {
    const int h = wv * 2 + hh;
    float wc[8];
    #pragma unroll
    for (int ct = 0; ct < 8; ++ct) wc[ct] = W[(size_t)h * DL + 16 * ct + r];

    #pragma unroll
    for (int rt = 0; rt < 4; ++rt) {
      const short* ap = mh + ((size_t)h * MTOT + row0 + 16 * rt + r) * DM + q * 8;
      bf16x8 a0 = *reinterpret_cast<const bf16x8*>(ap);
      bf16x8 a1 = *reinterpret_cast<const bf16x8*>(ap + 32);
      float sc[4] = {0.f, 0.f, 0.f, 0.f};
      #pragma unroll
      for (int ct = 0; ct < 8; ++ct) {
        const short* bp = Vt + (size_t)(16 * ct + r) * DM + q * 8;
        bf16x8 b0 = *reinterpret_cast<const bf16x8*>(bp);
        bf16x8 b1 = *reinterpret_cast<const bf16x8*>(bp + 32);
        f32x4 t = f32x4{0.f, 0.f, 0.f, 0.f};
        t = mfma_bf16(a0, b0, t);
        t = mfma_bf16(a1, b1, t);
        #pragma unroll
        for (int j = 0; j < 4; ++j) {
          int row = row0 + 16 * rt + 4 * q + j;
          int coll = 16 * ct + r;
          float g = b2f(gate[(size_t)row * DL + coll]);
          float d = tanhf(t[j]) * g;
          sc[j] += d * wc[ct];
        }
      }
      #pragma unroll
      for (int j = 0; j < 4; ++j) {
        sc[j] += __shfl_xor(sc[j], 1);
        sc[j] += __shfl_xor(sc[j], 2);
        sc[j] += __shfl_xor(sc[j], 4);
        sc[j] += __shfl_xor(sc[j], 8);
      }
      if (r < 4) {
        float v = (r == 0) ? sc[0] : (r == 1) ? sc[1] : (r == 2) ? sc[2] : sc[3];
        scores[(size_t)h * MTOT + row0 + 16 * rt + 4 * q + r] = v;
      }
    }
  }
}

// ---------------------------------------------------------------------------
// Kernel 4: masked softmax over N per (h,b). soft=0 for n >= true_num[b].
// Also writes head-0 softmax to the output (second tuple element).
// ---------------------------------------------------------------------------
__global__ __launch_bounds__(256) void softmax_kernel(
    const float* __restrict__ scores, const int* __restrict__ true_num,
    float* __restrict__ soft, float* __restrict__ out_soft) {
  const int h = blockIdx.x >> 3, b = blockIdx.x & 7;
  const int tid = threadIdx.x;
  const int tn = true_num[b];
  const float* s = scores + ((size_t)h * BBAG + b) * NINST;
  __shared__ float red[8];

  float vals[16];
  float mx = -3.0e38f;
  #pragma unroll
  for (int i = 0; i < 16; ++i) {
    int n = tid + i * 256;
    float v = s[n];
    vals[i] = (n < tn) ? v : -3.0e38f;
    mx = fmaxf(mx, vals[i]);
  }
  #pragma unroll
  for (int m = 1; m < 64; m <<= 1) mx = fmaxf(mx, __shfl_xor(mx, m));
  if ((tid & 63) == 0) red[tid >> 6] = mx;
  __syncthreads();
  mx = fmaxf(fmaxf(red[0], red[1]), fmaxf(red[2], red[3]));

  float sum = 0.f;
  #pragma unroll
  for (int i = 0; i < 16; ++i) {
    int n = tid + i * 256;
    float e = (n < tn) ? expf(vals[i] - mx) : 0.0f;
    vals[i] = e;
    sum += e;
  }
  #pragma unroll
  for (int m = 1; m < 64; m <<= 1) sum += __shfl_xor(sum, m);
  if ((tid & 63) == 0) red[4 + (tid >> 6)] = sum;
  __syncthreads();
  sum = red[4] + red[5] + red[6] + red[7];
  float inv = 1.0f / sum;

  float* so = soft + ((size_t)h * BBAG + b) * NINST;
  #pragma unroll
  for (int i = 0; i < 16; ++i) {
    int n = tid + i * 256;
    float v = vals[i] * inv;
    so[n] = v;
    if (h == 0) out_soft[(size_t)b * NINST + n] = v;
  }
}

// ---------------------------------------------------------------------------
// Kernel 5a: partial pooling. grid = (h,b,chunk): 8*8*8 = 512 blocks.
// part[(h*8+b)*NCHUNK+chunk][m] = sum_{n in chunk} soft[h][b][n]*mh[h][b*N+n][m]
// ---------------------------------------------------------------------------
__global__ __launch_bounds__(256) void pool_partial(
    const short* __restrict__ mh, const float* __restrict__ soft,
    float* __restrict__ part) {
  const int c = blockIdx.x & (NCHUNK - 1);
  const int hb = blockIdx.x / NCHUNK;        // h*8 + b
  const int h = hb >> 3, b = hb & 7;
  const int tid = threadIdx.x;
  const int m = tid & 63, g = tid >> 6;
  const int n0 = c * (NINST / NCHUNK);
  const float* so = soft + ((size_t)h * BBAG + b) * NINST;
  const short* mp = mh + ((size_t)h * MTOT + (size_t)b * NINST) * DM;
  float acc = 0.f;
  #pragma unroll 4
  for (int n = n0 + g; n < n0 + NINST / NCHUNK; n += 4) {
    acc += so[n] * b2f(mp[(size_t)n * DM + m]);
  }
  __shared__ float red[256];
  red[tid] = acc;
  __syncthreads();
  if (tid < 64) {
    part[(size_t)(hb * NCHUNK + c) * DM + tid] =
        red[tid] + red[tid + 64] + red[tid + 128] + red[tid + 192];
  }
}

// ---------------------------------------------------------------------------
// Kernel 5b: reduce partials -> feat[b][h*64+m]
// ---------------------------------------------------------------------------
__global__ __launch_bounds__(256) void pool_reduce(
    const float* __restrict__ part, float* __restrict__ out_feat) {
  int g = blockIdx.x * blockDim.x + threadIdx.x;   // 4096 outputs
  int hb = g >> 6, m = g & 63;
  int h = hb >> 3, b = hb & 7;
  float s = 0.f;
  #pragma unroll
  for (int c = 0; c < NCHUNK; ++c)
    s += part[(size_t)(hb * NCHUNK + c) * DM + m];
  out_feat[(size_t)b * (NHEAD * DM) + h * DM + m] = s;
}

// ---------------------------------------------------------------------------
extern "C" void kernel_launch(void* const* d_in, const int* in_sizes, int n_in,
                              void* d_out, int out_size, void* d_ws, size_t ws_size,
                              hipStream_t stream) {
  (void)in_sizes; (void)n_in; (void)out_size; (void)ws_size;
  const float* x      = (const float*)d_in[0];
  const float* WX     = (const float*)d_in[1];
  const float* V      = (const float*)d_in[2];
  const float* W      = (const float*)d_in[3];
  const float* gate_w = (const float*)d_in[4];
  const int* true_num = (const int*)d_in[5];
  float* out = (float*)d_out;

  char* ws = (char*)d_ws;
  short* Wt2    = (short*)ws;  ws += (size_t)NCOL * DIM * 2;            //    655,360 B
  short* Vt     = (short*)ws;  ws += (size_t)DL * DM * 2;               //     16,384 B
  short* mh     = (short*)ws;  ws += (size_t)NHEAD * MTOT * DM * 2;     // 33,554,432 B
  short* gate   = (short*)ws;  ws += (size_t)MTOT * DL * 2;             //  8,388,608 B
  float* scores = (float*)ws;  ws += (size_t)NHEAD * MTOT * 4;          //  1,048,576 B
  float* soft   = (float*)ws;  ws += (size_t)NHEAD * MTOT * 4;          //  1,048,576 B
  float* part   = (float*)ws;  ws += (size_t)NHEAD * BBAG * NCHUNK * DM * 4; // 131,072 B

  prep_weights<<<dim3((16 * 640 * 4 + DL * DM + 255) / 256), dim3(256), 0, stream>>>(
      WX, V, gate_w, Wt2, Vt);
  proj_kernel<<<dim3(MTOT / 64), dim3(512), 0, stream>>>(x, Wt2, mh, gate);
  score_kernel<<<dim3(MTOT / 64), dim3(256), 0, stream>>>(mh, gate, Vt, W, scores);
  softmax_kernel<<<dim3(NHEAD * BBAG), dim3(256), 0, stream>>>(
      scores, true_num, soft, out + BBAG * NHEAD * DM);
  pool_partial<<<dim3(NHEAD * BBAG * NCHUNK), dim3(256), 0, stream>>>(mh, soft, part);
  pool_reduce<<<dim3(NHEAD * BBAG * DM / 256), dim3(256), 0, stream>>>(part, out);
}

// Round 6
// 119.949 us; speedup vs baseline: 1.1185x; 1.0004x over previous
//
#include <hip/hip_runtime.h>
#include <hip/hip_bf16.h>

#define DIM   512
#define NHEAD 8
#define DM    64
#define DL    128
#define BBAG  8
#define NINST 4096
#define MTOT  (BBAG*NINST)     // 32768 instances
#define NCOL  (NHEAD*DM + DL)  // 640 fused output columns (8*64 mh + 128 gate)
#define NCHUNK 8               // pool n-chunks per (h,b)

typedef short   bf16x8 __attribute__((ext_vector_type(8)));
typedef __bf16  bf16v8 __attribute__((ext_vector_type(8)));
typedef float   f32x4  __attribute__((ext_vector_type(4)));
typedef short   s16x4  __attribute__((ext_vector_type(4)));

__device__ __forceinline__ short f2b(float f) {
  __hip_bfloat16 h = __float2bfloat16(f);
  return __builtin_bit_cast(short, h);
}
__device__ __forceinline__ float b2f(short s) {
  __hip_bfloat16 h = __builtin_bit_cast(__hip_bfloat16, s);
  return __bfloat162float(h);
}
__device__ __forceinline__ f32x4 mfma_bf16(bf16x8 a, bf16x8 b, f32x4 c) {
  return __builtin_amdgcn_mfma_f32_16x16x32_bf16(
      __builtin_bit_cast(bf16v8, a), __builtin_bit_cast(bf16v8, b), c, 0, 0, 0);
}

// ---------------------------------------------------------------------------
// Kernel 1: build bf16 weights (slab-major, pre-swizzled; see R2 notes).
// Wt2 shorts[ks*20480 + col*32 + q2*8], q2 = (q + ((col&15)>>1)) & 3.
// Vt[l][m] = V[m][l]
// ---------------------------------------------------------------------------
__global__ void prep_weights(const float* __restrict__ WX, const float* __restrict__ V,
                             const float* __restrict__ gate_w,
                             short* __restrict__ Wt2, short* __restrict__ Vt) {
  int g = blockIdx.x * blockDim.x + threadIdx.x;
  if (g < 16 * 640 * 4) {               // 40960 16-byte pieces of Wt2
    int ks = g / 2560;
    int rem = g - ks * 2560;
    int col = rem >> 2, q = rem & 3;
    int q2 = (q + ((col & 15) >> 1)) & 3;
    short* dst = Wt2 + ks * 20480 + col * 32 + q2 * 8;
    #pragma unroll
    for (int j = 0; j < 8; ++j) {
      int k = ks * 32 + q * 8 + j;
      float v;
      if (col < NHEAD * DM) v = WX[((size_t)(col >> 6) * DIM + k) * DM + (col & 63)];
      else                  v = gate_w[(size_t)k * DL + (col - NHEAD * DM)];
      dst[j] = f2b(v);
    }
  } else {
    int i = g - 16 * 640 * 4;
    if (i < DL * DM) {
      int l = i >> 6, m = i & 63;
      Vt[(size_t)l * DM + m] = f2b(V[(size_t)m * DL + l]);
    }
  }
}

// ---------------------------------------------------------------------------
// Kernel 2: fused projection GEMM  C[32768 x 640] = x[32768 x 512] * Wcat
// 2-phase pipelined (T3-min): A (64x512 bf16, 64 KB) staged ONCE in prologue;
// B double-buffered (2 x 40 KB), stage(ks+1) issued BEFORE compute(ks),
// ONE barrier per K-step. LDS 144 KB -> 1 block/CU; latency hidden by
// 1-deep prefetch instead of residency.
// ---------------------------------------------------------------------------
__global__ __launch_bounds__(512) void proj_kernel(
    const float* __restrict__ x, const short* __restrict__ Wt2,
    short* __restrict__ mh, short* __restrict__ gate) {
  __shared__ alignas(1024) short lds_b[2][20480];  // 2 x 40 KB B slabs (swizzled)
  __shared__ alignas(16)   short lds_a[32768];     // 64 KB: 16 slabs [64r][32k] swz
  const int tid = threadIdx.x;
  const int bm0 = blockIdx.x * 64;
  const int lane = tid & 63;
  const int w = tid >> 6;            // wave 0..7 -> cols [80w, 80w+80)
  const int r = lane & 15;
  const int q = lane >> 4;           // 0..3
  const int swz = ((q + (r >> 1)) & 3) * 16;  // bank-quad swizzle byte offset

  char* lda = reinterpret_cast<char*>(lds_a);
  char* ldb = reinterpret_cast<char*>(lds_b);

  // ---- prologue: stage whole A tile (all 16 K-steps) f32->bf16 ----
  const int arow = tid >> 3, ap = tid & 7;
  const int aslot = ((ap >> 1) + ((arow & 15) >> 1)) & 3;
  const float* asrc = x + ((size_t)(bm0 + arow) << 9) + (ap << 2);
  char* adst0 = lda + arow * 64 + aslot * 16 + (ap & 1) * 8;
  #pragma unroll 4
  for (int ks = 0; ks < 16; ++ks) {
    float4 av = *reinterpret_cast<const float4*>(asrc + ks * 32);
    s16x4 as;
    as.x = f2b(av.x); as.y = f2b(av.y); as.z = f2b(av.z); as.w = f2b(av.w);
    *reinterpret_cast<s16x4*>(adst0 + ks * 4096) = as;
  }
  // ---- stage B slab for ks=0 into buf 0 ----
  #pragma unroll
  for (int i = 0; i < 5; ++i) {
    const int unit = w * 5 + i;
    const short* gsrc = Wt2 + 0 * 20480 + unit * 512 + lane * 8;
    __builtin_amdgcn_global_load_lds(
        (const __attribute__((address_space(1))) void*)gsrc,
        (__attribute__((address_space(3))) void*)(ldb + unit * 1024),
        16, 0, 0);
  }
  __syncthreads();

  f32x4 acc[4][5];
  #pragma unroll
  for (int rt = 0; rt < 4; ++rt)
    #pragma unroll
    for (int ct = 0; ct < 5; ++ct) acc[rt][ct] = f32x4{0.f, 0.f, 0.f, 0.f};

  for (int ks = 0; ks < 16; ++ks) {
    const int cur = ks & 1;
    // --- issue prefetch of slab ks+1 into buf cur^1 (before compute!) ---
    if (ks < 15) {
      #pragma unroll
      for (int i = 0; i < 5; ++i) {
        const int unit = w * 5 + i;
        const short* gsrc = Wt2 + (ks + 1) * 20480 + unit * 512 + lane * 8;
        __builtin_amdgcn_global_load_lds(
            (const __attribute__((address_space(1))) void*)gsrc,
            (__attribute__((address_space(3))) void*)(ldb + (cur ^ 1) * 40960 + unit * 1024),
            16, 0, 0);
      }
    }
    // --- compute on buf cur: 4 A-frags, 5 B-frags, 20 MFMA ---
    bf16x8 af[4];
    #pragma unroll
    for (int rt = 0; rt < 4; ++rt)
      af[rt] = *reinterpret_cast<const bf16x8*>(
          lda + ks * 4096 + (16 * rt + r) * 64 + swz);
    #pragma unroll
    for (int ct = 0; ct < 5; ++ct) {
      bf16x8 bf = *reinterpret_cast<const bf16x8*>(
          ldb + cur * 40960 + (80 * w + 16 * ct + r) * 64 + swz);
      #pragma unroll
      for (int rt = 0; rt < 4; ++rt)
        acc[rt][ct] = mfma_bf16(af[rt], bf, acc[rt][ct]);
    }
    // one barrier per step: publishes buf cur^1 (vmcnt drained) and retires
    // this step's ds_reads (lgkm drained) before buf cur is overwritten.
    __syncthreads();
  }

  // epilogue: D-frag lane mapping row = 4q+j (+16rt), col = r (+16ct)
  #pragma unroll
  for (int rt = 0; rt < 4; ++rt) {
    #pragma unroll
    for (int ct = 0; ct < 5; ++ct) {
      int col = 80 * w + 16 * ct + r;
      #pragma unroll
      for (int j = 0; j < 4; ++j) {
        int grow = bm0 + 16 * rt + 4 * q + j;
        float v = acc[rt][ct][j];
        if (col < NHEAD * DM) {
          mh[((size_t)(col >> 6) * MTOT + grow) * DM + (col & 63)] = f2b(v);
        } else {
          gate[(size_t)grow * DL + (col - NHEAD * DM)] = f2b(1.0f / (1.0f + expf(-v)));
        }
      }
    }
  }
}

// ---------------------------------------------------------------------------
// Kernel 3: scores[h][row] = sum_l tanh( (mh_h . V)[row][l] ) * gate[row][l] * W[h][l]
// ---------------------------------------------------------------------------
__global__ __launch_bounds__(256) void score_kernel(
    const short* __restrict__ mh, const short* __restrict__ gate,
    const short* __restrict__ Vt, const float* __restrict__ W,
    float* __restrict__ scores) {
  const int tid = threadIdx.x;
  const int lane = tid & 63;
  const int wv = tid >> 6;         // 0..3
  const int r = lane & 15, q = lane >> 4;
  const int row0 = blockIdx.x * 64;

  #pragma unroll
  for (int hh = 0; hh < 2; ++hh) {
    const int h = wv * 2 + hh;
    float wc[8];
    #pragma unroll
    for (int ct = 0; ct < 8; ++ct) wc[ct] = W[(size_t)h * DL + 16 * ct + r];

    #pragma unroll
    for (int rt = 0; rt < 4; ++rt) {
      const short* ap = mh + ((size_t)h * MTOT + row0 + 16 * rt + r) * DM + q * 8;
      bf16x8 a0 = *reinterpret_cast<const bf16x8*>(ap);
      bf16x8 a1 = *reinterpret_cast<const bf16x8*>(ap + 32);
      float sc[4] = {0.f, 0.f, 0.f, 0.f};
      #pragma unroll
      for (int ct = 0; ct < 8; ++ct) {
        const short* bp = Vt + (size_t)(16 * ct + r) * DM + q * 8;
        bf16x8 b0 = *reinterpret_cast<const bf16x8*>(bp);
        bf16x8 b1 = *reinterpret_cast<const bf16x8*>(bp + 32);
        f32x4 t = f32x4{0.f, 0.f, 0.f, 0.f};
        t = mfma_bf16(a0, b0, t);
        t = mfma_bf16(a1, b1, t);
        #pragma unroll
        for (int j = 0; j < 4; ++j) {
          int row = row0 + 16 * rt + 4 * q + j;
          int coll = 16 * ct + r;
          float g = b2f(gate[(size_t)row * DL + coll]);
          float d = tanhf(t[j]) * g;
          sc[j] += d * wc[ct];
        }
      }
      #pragma unroll
      for (int j = 0; j < 4; ++j) {
        sc[j] += __shfl_xor(sc[j], 1);
        sc[j] += __shfl_xor(sc[j], 2);
        sc[j] += __shfl_xor(sc[j], 4);
        sc[j] += __shfl_xor(sc[j], 8);
      }
      if (r < 4) {
        float v = (r == 0) ? sc[0] : (r == 1) ? sc[1] : (r == 2) ? sc[2] : sc[3];
        scores[(size_t)h * MTOT + row0 + 16 * rt + 4 * q + r] = v;
      }
    }
  }
}

// ---------------------------------------------------------------------------
// Kernel 4: masked softmax over N per (h,b). soft=0 for n >= true_num[b].
// ---------------------------------------------------------------------------
__global__ __launch_bounds__(256) void softmax_kernel(
    const float* __restrict__ scores, const int* __restrict__ true_num,
    float* __restrict__ soft, float* __restrict__ out_soft) {
  const int h = blockIdx.x >> 3, b = blockIdx.x & 7;
  const int tid = threadIdx.x;
  const int tn = true_num[b];
  const float* s = scores + ((size_t)h * BBAG + b) * NINST;
  __shared__ float red[8];

  float vals[16];
  float mx = -3.0e38f;
  #pragma unroll
  for (int i = 0; i < 16; ++i) {
    int n = tid + i * 256;
    float v = s[n];
    vals[i] = (n < tn) ? v : -3.0e38f;
    mx = fmaxf(mx, vals[i]);
  }
  #pragma unroll
  for (int m = 1; m < 64; m <<= 1) mx = fmaxf(mx, __shfl_xor(mx, m));
  if ((tid & 63) == 0) red[tid >> 6] = mx;
  __syncthreads();
  mx = fmaxf(fmaxf(red[0], red[1]), fmaxf(red[2], red[3]));

  float sum = 0.f;
  #pragma unroll
  for (int i = 0; i < 16; ++i) {
    int n = tid + i * 256;
    float e = (n < tn) ? expf(vals[i] - mx) : 0.0f;
    vals[i] = e;
    sum += e;
  }
  #pragma unroll
  for (int m = 1; m < 64; m <<= 1) sum += __shfl_xor(sum, m);
  if ((tid & 63) == 0) red[4 + (tid >> 6)] = sum;
  __syncthreads();
  sum = red[4] + red[5] + red[6] + red[7];
  float inv = 1.0f / sum;

  float* so = soft + ((size_t)h * BBAG + b) * NINST;
  #pragma unroll
  for (int i = 0; i < 16; ++i) {
    int n = tid + i * 256;
    float v = vals[i] * inv;
    so[n] = v;
    if (h == 0) out_soft[(size_t)b * NINST + n] = v;
  }
}

// ---------------------------------------------------------------------------
// Kernel 5a: partial pooling. grid = (h,b,chunk): 8*8*8 = 512 blocks.
// ---------------------------------------------------------------------------
__global__ __launch_bounds__(256) void pool_partial(
    const short* __restrict__ mh, const float* __restrict__ soft,
    float* __restrict__ part) {
  const int c = blockIdx.x & (NCHUNK - 1);
  const int hb = blockIdx.x / NCHUNK;        // h*8 + b
  const int h = hb >> 3, b = hb & 7;
  const int tid = threadIdx.x;
  const int m = tid & 63, g = tid >> 6;
  const int n0 = c * (NINST / NCHUNK);
  const float* so = soft + ((size_t)h * BBAG + b) * NINST;
  const short* mp = mh + ((size_t)h * MTOT + (size_t)b * NINST) * DM;
  float acc = 0.f;
  #pragma unroll 4
  for (int n = n0 + g; n < n0 + NINST / NCHUNK; n += 4) {
    acc += so[n] * b2f(mp[(size_t)n * DM + m]);
  }
  __shared__ float red[256];
  red[tid] = acc;
  __syncthreads();
  if (tid < 64) {
    part[(size_t)(hb * NCHUNK + c) * DM + tid] =
        red[tid] + red[tid + 64] + red[tid + 128] + red[tid + 192];
  }
}

// ---------------------------------------------------------------------------
// Kernel 5b: reduce partials -> feat[b][h*64+m]
// ---------------------------------------------------------------------------
__global__ __launch_bounds__(256) void pool_reduce(
    const float* __restrict__ part, float* __restrict__ out_feat) {
  int g = blockIdx.x * blockDim.x + threadIdx.x;   // 4096 outputs
  int hb = g >> 6, m = g & 63;
  int h = hb >> 3, b = hb & 7;
  float s = 0.f;
  #pragma unroll
  for (int c = 0; c < NCHUNK; ++c)
    s += part[(size_t)(hb * NCHUNK + c) * DM + m];
  out_feat[(size_t)b * (NHEAD * DM) + h * DM + m] = s;
}

// ---------------------------------------------------------------------------
extern "C" void kernel_launch(void* const* d_in, const int* in_sizes, int n_in,
                              void* d_out, int out_size, void* d_ws, size_t ws_size,
                              hipStream_t stream) {
  (void)in_sizes; (void)n_in; (void)out_size; (void)ws_size;
  const float* x      = (const float*)d_in[0];
  const float* WX     = (const float*)d_in[1];
  const float* V      = (const float*)d_in[2];
  const float* W      = (const float*)d_in[3];
  const float* gate_w = (const float*)d_in[4];
  const int* true_num = (const int*)d_in[5];
  float* out = (float*)d_out;

  char* ws = (char*)d_ws;
  short* Wt2    = (short*)ws;  ws += (size_t)NCOL * DIM * 2;            //    655,360 B
  short* Vt     = (short*)ws;  ws += (size_t)DL * DM * 2;               //     16,384 B
  short* mh     = (short*)ws;  ws += (size_t)NHEAD * MTOT * DM * 2;     // 33,554,432 B
  short* gate   = (short*)ws;  ws += (size_t)MTOT * DL * 2;             //  8,388,608 B
  float* scores = (float*)ws;  ws += (size_t)NHEAD * MTOT * 4;          //  1,048,576 B
  float* soft   = (float*)ws;  ws += (size_t)NHEAD * MTOT * 4;          //  1,048,576 B
  float* part   = (float*)ws;  ws += (size_t)NHEAD * BBAG * NCHUNK * DM * 4; // 131,072 B

  prep_weights<<<dim3((16 * 640 * 4 + DL * DM + 255) / 256), dim3(256), 0, stream>>>(
      WX, V, gate_w, Wt2, Vt);
  proj_kernel<<<dim3(MTOT / 64), dim3(512), 0, stream>>>(x, Wt2, mh, gate);
  score_kernel<<<dim3(MTOT / 64), dim3(256), 0, stream>>>(mh, gate, Vt, W, scores);
  softmax_kernel<<<dim3(NHEAD * BBAG), dim3(256), 0, stream>>>(
      scores, true_num, soft, out + BBAG * NHEAD * DM);
  pool_partial<<<dim3(NHEAD * BBAG * NCHUNK), dim3(256), 0, stream>>>(mh, soft, part);
  pool_reduce<<<dim3(NHEAD * BBAG * DM / 256), dim3(256), 0, stream>>>(part, out);
}